// Round 7
// baseline (210.042 us; speedup 1.0000x reference)
//
#include <hip/hip_runtime.h>
#include <math.h>

#define SS 2048
#define DD 1024
#define HH 16
#define NQKV 3072
#define MROWS 4096
#define KD 1024

typedef __attribute__((ext_vector_type(8))) short bf16x8;
typedef __attribute__((ext_vector_type(8))) unsigned short us8;
typedef __attribute__((ext_vector_type(4))) float f32x4;
typedef unsigned short u16;
typedef unsigned int u32;

#define SCALE_C 0.18033688011112042f  // log2(e)/sqrt(64), folded into Q at GEMM epilogue

// async global->LDS, 16B per lane; LDS dst = wave-uniform base + lane*16
#define GLDS16(g, l) \
  __builtin_amdgcn_global_load_lds((const __attribute__((address_space(1))) u32*)(g), \
                                   (__attribute__((address_space(3))) u32*)(l), 16, 0, 0)

static __device__ __forceinline__ u16 f2bf(float f) {
  union { float f; u32 u; } v; v.f = f;
  u32 u = v.u;
  u += 0x7fffu + ((u >> 16) & 1u);   // RNE
  return (u16)(u >> 16);
}
static __device__ __forceinline__ float bf2f(u16 x) {
  union { u32 u; float f; } v; v.u = ((u32)x) << 16; return v.f;
}
static __device__ __forceinline__ u32 pk2(float a, float b) {      // RNE pack
  return (u32)f2bf(a) | ((u32)f2bf(b) << 16);
}
static __device__ __forceinline__ u32 pk2t(float a, float b) {     // truncating pack, 1 v_perm
  union { float f; u32 u; } ua, ub; ua.f = a; ub.f = b;
  return __builtin_amdgcn_perm(ub.u, ua.u, 0x07060302u);
}

// ---- merged prep: x convert (blocks 0..2047), w_qkv T (2048..2815), w_proj T (2816..3071) ----
__global__ __launch_bounds__(256) void k_prep(const float* __restrict__ x,
                                              const float* __restrict__ w_qkv,
                                              const float* __restrict__ w_proj,
                                              u16* __restrict__ x_bf,
                                              u16* __restrict__ wqkvT,
                                              u16* __restrict__ wprojT) {
  __shared__ float t[64][65];
  int bx = blockIdx.x;
  int tid = threadIdx.x;
  if (bx < 2048) {
    int i = (bx * 256 + tid) * 8;
    float4 a = *(const float4*)(x + i);
    float4 b = *(const float4*)(x + i + 4);
    us8 o;
    o[0] = f2bf(a.x); o[1] = f2bf(a.y); o[2] = f2bf(a.z); o[3] = f2bf(a.w);
    o[4] = f2bf(b.x); o[5] = f2bf(b.y); o[6] = f2bf(b.z); o[7] = f2bf(b.w);
    *(us8*)(x_bf + i) = o;
    return;
  }
  const float* in; u16* out; int R = KD, C, tile;
  if (bx < 2048 + 768) { in = w_qkv; out = wqkvT; C = NQKV; tile = bx - 2048; }
  else                 { in = w_proj; out = wprojT; C = DD; tile = bx - 2816; }
  int tilesC = C >> 6;
  int tc = tile % tilesC, tr = tile / tilesC;
  int r0 = tr * 64, c0 = tc * 64;
  int lx = tid & 63, ly = tid >> 6;
#pragma unroll
  for (int i = 0; i < 16; i++) {
    int rr = ly + i * 4;
    t[rr][lx] = in[(size_t)(r0 + rr) * C + c0 + lx];
  }
  __syncthreads();
#pragma unroll
  for (int i = 0; i < 16; i++) {
    int cc = ly + i * 4;
    out[(size_t)(c0 + cc) * R + r0 + lx] = f2bf(t[lx][cc]);
  }
}

// ---- bf16 GEMM, m97-class staging. BM = 128 or 64 rows per block.
// MODE 0: f32 out. MODE 2 (BM=128): bf16 qkv out; Q cols (n<1024) pre-scaled by
// SCALE_C; V cols (n>=2048) written ONLY transposed to vt[(b*16+h)*64+d][s]. ----
template <int MODE, int BM>
__global__ __launch_bounds__(256, 2) void k_gemm(const u16* __restrict__ A,
                                                 const u16* __restrict__ Bt,
                                                 const float* __restrict__ bias,
                                                 void* __restrict__ Cout,
                                                 u16* __restrict__ vt,
                                                 int M, int N, int K) {
  constexpr int MT = BM / 32;               // row-subtiles per wave: 4 or 2
  __shared__ alignas(16) u16 As[BM * 32];   // rows 64B, XOR-swizzled 16B chunks
  __shared__ alignas(16) u16 Bs[128 * 32];
  const int tid = threadIdx.x;
  const int w = tid >> 6, ln = tid & 63;
  const int wm = w >> 1, wn = w & 1;
  const int lm = ln & 15, quad = ln >> 4;
  const int m0 = blockIdx.y * BM, n0 = blockIdx.x * 128;
  const int lr = ln >> 2, c = ln & 3;
  const int cg = c ^ (lr & 3);

  f32x4 acc[MT][4];
#pragma unroll
  for (int i = 0; i < MT; i++)
#pragma unroll
    for (int j = 0; j < 4; j++) acc[i][j] = (f32x4){0.f, 0.f, 0.f, 0.f};

  const u16* gA0 = A  + (size_t)(m0 + 16 * w       + lr) * K + cg * 8;
  const u16* gA1 = A  + (size_t)(m0 + 16 * (w + 4) + lr) * K + cg * 8;  // BM=128 only
  const u16* gB0 = Bt + (size_t)(n0 + 16 * w       + lr) * K + cg * 8;
  const u16* gB1 = Bt + (size_t)(n0 + 16 * (w + 4) + lr) * K + cg * 8;
  char* lA0 = (char*)As + w * 1024;
  char* lA1 = (char*)As + (w + 4) * 1024;
  char* lB0 = (char*)Bs + w * 1024;
  char* lB1 = (char*)Bs + (w + 4) * 1024;

  for (int k0 = 0; k0 < K; k0 += 32) {
    GLDS16(gA0 + k0, lA0);
    if (BM == 128) GLDS16(gA1 + k0, lA1);
    GLDS16(gB0 + k0, lB0);
    GLDS16(gB1 + k0, lB1);
    __syncthreads();
    bf16x8 af[MT], bfr[4];
#pragma unroll
    for (int t = 0; t < MT; t++)
      af[t]  = *(const bf16x8*)((const char*)As + (wm * (MT * 16) + t * 16 + lm) * 64 + ((quad ^ (lm & 3)) * 16));
#pragma unroll
    for (int t = 0; t < 4; t++)
      bfr[t] = *(const bf16x8*)((const char*)Bs + (wn * 64 + t * 16 + lm) * 64 + ((quad ^ (lm & 3)) * 16));
#pragma unroll
    for (int mt = 0; mt < MT; mt++)
#pragma unroll
      for (int nt = 0; nt < 4; nt++)
        acc[mt][nt] = __builtin_amdgcn_mfma_f32_16x16x32_bf16(af[mt], bfr[nt], acc[mt][nt], 0, 0, 0);
    __syncthreads();
  }

  float bv[4];
#pragma unroll
  for (int nt = 0; nt < 4; nt++) bv[nt] = bias[n0 + wn * 64 + nt * 16 + lm];

  if (MODE == 2 && n0 >= 2 * DD) {
    // V tile: write transposed to vt. All rows of this tile share b.
    int b = m0 >> 11;
    int s0 = (m0 & 2047) + wm * 64;
#pragma unroll
    for (int mt = 0; mt < MT; mt++) {
      int s = s0 + mt * 16 + quad * 4;
#pragma unroll
      for (int nt = 0; nt < 4; nt++) {
        int n = n0 + wn * 64 + nt * 16 + lm;
        int bh = b * HH + ((n - 2 * DD) >> 6);
        int d = n & 63;
        uint2 v;
        v.x = pk2(acc[mt][nt][0] + bv[nt], acc[mt][nt][1] + bv[nt]);
        v.y = pk2(acc[mt][nt][2] + bv[nt], acc[mt][nt][3] + bv[nt]);
        *(uint2*)&vt[(size_t)(bh * 64 + d) * SS + s] = v;
      }
    }
    return;
  }

  const float qs = (MODE == 2 && n0 < DD) ? SCALE_C : 1.0f;  // fold softmax scale into Q
#pragma unroll
  for (int mt = 0; mt < MT; mt++) {
#pragma unroll
    for (int r = 0; r < 4; r++) {
      int row = m0 + wm * (MT * 16) + mt * 16 + quad * 4 + r;
#pragma unroll
      for (int nt = 0; nt < 4; nt++) {
        int col = n0 + wn * 64 + nt * 16 + lm;
        float v = (acc[mt][nt][r] + bv[nt]) * qs;
        if (MODE == 2) ((u16*)Cout)[(size_t)row * N + col] = f2bf(v);
        else           ((float*)Cout)[(size_t)row * N + col] = v;
      }
    }
  }
}

// ---- flash attention, split-KV x2: block = (half, b, h, 128 q rows); grid 1024.
//      Static softmax => partials exactly additive. P via per-wave Ps LDS
//      (16 rows, reused for qs2=0/1; XOR-swizzled 128B rows, no padding).
//      LDS 40KB -> 4 blocks/CU, all 1024 blocks resident. ----
__global__ __launch_bounds__(256, 4) void k_attn(const u16* __restrict__ qkv,
                                                 const u16* __restrict__ vt,
                                                 u16* __restrict__ po0,
                                                 u16* __restrict__ po1,
                                                 float* __restrict__ lb0,
                                                 float* __restrict__ lb1) {
  __shared__ alignas(16) u16 Ks[2][64 * 64];    // dbuf [key][d]   16 KB
  __shared__ alignas(16) u16 Vs[2][64 * 64];    // dbuf [d][key]   16 KB
  __shared__ alignas(16) u16 Ps[4 * 16 * 64];   // per-wave 16x128B, swizzled, 8 KB

  const int tid = threadIdx.x;
  const int w = tid >> 6, ln = tid & 63;
  const int lm = ln & 15, quad = ln >> 4;
  const int bx = blockIdx.x;
  const int half = bx >> 9;
  const int bxx = bx & 511;
  const int bh = bxx >> 4;
  const int q0 = (bxx & 15) * 128;
  const int b = bh >> 4, h = bh & 15;
  const size_t qkv_b = (size_t)b * SS * NQKV;
  const int hcol = h * 64;
  const int kvoff = half * (SS / 2);            // this block's 1024-key range

  u16* __restrict__ po = half ? po1 : po0;
  float* __restrict__ lb = half ? lb1 : lb0;

  const int lr = ln >> 3, cc = ln & 7;
  const int cg = cc ^ lr;   // XOR-swizzled source chunk (row&7 == lr)

  // Q straight to registers: 4 x 16B per lane, once per block (already *SCALE_C)
  bf16x8 qf[2][2];
#pragma unroll
  for (int qs2 = 0; qs2 < 2; qs2++)
#pragma unroll
    for (int kk = 0; kk < 2; kk++)
      qf[qs2][kk] = *(const bf16x8*)(qkv + qkv_b +
                     (size_t)(q0 + w * 32 + qs2 * 16 + lm) * NQKV + hcol + kk * 32 + quad * 8);

  f32x4 o[4][2];
  float l[2] = {0.f, 0.f};
#pragma unroll
  for (int t = 0; t < 4; t++) { o[t][0] = (f32x4){0, 0, 0, 0}; o[t][1] = (f32x4){0, 0, 0, 0}; }

  char* psw = (char*)Ps + w * 2048;             // this wave's 16x128B region

  // stage K/V tile 0 of this half into buf 0
#pragma unroll
  for (int rr = 0; rr < 2; rr++) {
    int i = w + 4 * rr;
    GLDS16(qkv + qkv_b + (size_t)(kvoff + 8 * i + lr) * NQKV + DD + hcol + cg * 8, (char*)Ks[0] + i * 1024);
    GLDS16(vt + (size_t)(bh * 64 + 8 * i + lr) * SS + kvoff + cg * 8,              (char*)Vs[0] + i * 1024);
  }

#pragma unroll 1
  for (int it = 0; it < 16; it++) {
    __syncthreads();   // drains tile-it loads (issued one compute-phase ago)

    if (it + 1 < 16) {
      int kv1 = kvoff + (it + 1) * 64;
      char* kd = (char*)Ks[(it + 1) & 1];
      char* vd = (char*)Vs[(it + 1) & 1];
#pragma unroll
      for (int rr = 0; rr < 2; rr++) {
        int i = w + 4 * rr;
        GLDS16(qkv + qkv_b + (size_t)(kv1 + 8 * i + lr) * NQKV + DD + hcol + cg * 8, kd + i * 1024);
        GLDS16(vt + (size_t)(bh * 64 + 8 * i + lr) * SS + kv1 + cg * 8,              vd + i * 1024);
      }
    }

    const char* ksb = (const char*)Ks[it & 1];
    const char* vsb = (const char*)Vs[it & 1];

    // S^T = K · Q^T  (C: col = q = lane&15, row = key = quad*4+r (+16t))
    f32x4 s[4][2];
#pragma unroll
    for (int t = 0; t < 4; t++) { s[t][0] = (f32x4){0, 0, 0, 0}; s[t][1] = (f32x4){0, 0, 0, 0}; }
#pragma unroll
    for (int kk = 0; kk < 2; kk++)
#pragma unroll
      for (int t = 0; t < 4; t++) {
        bf16x8 kf = *(const bf16x8*)(ksb + (t * 16 + lm) * 128 + (((kk * 4 + quad) ^ (lm & 7)) * 16));
        s[t][0] = __builtin_amdgcn_mfma_f32_16x16x32_bf16(kf, qf[0][kk], s[t][0], 0, 0, 0);
        s[t][1] = __builtin_amdgcn_mfma_f32_16x16x32_bf16(kf, qf[1][kk], s[t][1], 0, 0, 0);
      }

    // V fragments: one read per tile, shared by both qs2
    bf16x8 vf[2][4];
#pragma unroll
    for (int kk = 0; kk < 2; kk++)
#pragma unroll
      for (int t = 0; t < 4; t++)
        vf[kk][t] = *(const bf16x8*)(vsb + (t * 16 + lm) * 128 + (((kk * 4 + quad) ^ (lm & 7)) * 16));

    // per qs2: exp2, sum, Ps write (swizzled), Ps read as B-frag, PV MFMAs.
    // Ps reused across qs2 — safe via per-wave DS program order.
#pragma unroll
    for (int qs2 = 0; qs2 < 2; qs2++) {
      float sum = 0.f;
      u32 pkv[4][2];
#pragma unroll
      for (int t = 0; t < 4; t++) {
        float p0 = __builtin_amdgcn_exp2f(s[t][qs2][0]);
        float p1 = __builtin_amdgcn_exp2f(s[t][qs2][1]);
        float p2 = __builtin_amdgcn_exp2f(s[t][qs2][2]);
        float p3 = __builtin_amdgcn_exp2f(s[t][qs2][3]);
        sum += (p0 + p1) + (p2 + p3);
        pkv[t][0] = pk2t(p0, p1);
        pkv[t][1] = pk2t(p2, p3);
      }
      sum += __shfl_xor(sum, 16);
      sum += __shfl_xor(sum, 32);
      l[qs2] += sum;
      // write keys t*16+quad*4+{0..3} at row lm: unswizzled byte off 32t+8*quad
#pragma unroll
      for (int t = 0; t < 4; t++) {
        uint2 v; v.x = pkv[t][0]; v.y = pkv[t][1];
        *(uint2*)(psw + lm * 128 + (((2 * t + (quad >> 1)) ^ (lm & 7)) * 16) + (quad & 1) * 8) = v;
      }
      bf16x8 pf0 = *(const bf16x8*)(psw + lm * 128 + (((0 + quad) ^ (lm & 7)) * 16));
      bf16x8 pf1 = *(const bf16x8*)(psw + lm * 128 + (((4 + quad) ^ (lm & 7)) * 16));
#pragma unroll
      for (int t = 0; t < 4; t++) {
        o[t][qs2] = __builtin_amdgcn_mfma_f32_16x16x32_bf16(vf[0][t], pf0, o[t][qs2], 0, 0, 0);
        o[t][qs2] = __builtin_amdgcn_mfma_f32_16x16x32_bf16(vf[1][t], pf1, o[t][qs2], 0, 0, 0);
      }
    }
  }

  // store UNNORMALIZED partial O (bf16) + partial l (combine kernel normalizes)
#pragma unroll
  for (int qs2 = 0; qs2 < 2; qs2++) {
    int qg = q0 + w * 32 + qs2 * 16 + lm;
    if (quad == 0) lb[(size_t)bh * SS + qg] = l[qs2];
    int row = b * SS + qg;
#pragma unroll
    for (int t = 0; t < 4; t++) {
      uint2 v;
      v.x = pk2(o[t][qs2][0], o[t][qs2][1]);
      v.y = pk2(o[t][qs2][2], o[t][qs2][3]);
      *(uint2*)&po[(size_t)row * DD + hcol + t * 16 + quad * 4] = v;
    }
  }
}

// ---- combine: attn = (po0 + po1) / (l0 + l1), in place over po0 ----
__global__ __launch_bounds__(256) void k_comb(u16* __restrict__ po0,
                                              const u16* __restrict__ po1,
                                              const float* __restrict__ l0,
                                              const float* __restrict__ l1) {
  int i = (blockIdx.x * 256 + threadIdx.x) * 8;
  int row = i >> 10, col = i & 1023;
  int h = col >> 6, b = row >> 11, q = row & 2047;
  size_t li = (size_t)(b * HH + h) * SS + q;
  float il = 1.0f / (l0[li] + l1[li]);
  us8 a = *(const us8*)(po0 + i);
  us8 p = *(const us8*)(po1 + i);
  us8 o;
#pragma unroll
  for (int j = 0; j < 8; j++) o[j] = f2bf((bf2f(a[j]) + bf2f(p[j])) * il);
  *(us8*)(po0 + i) = o;
}

extern "C" void kernel_launch(void* const* d_in, const int* in_sizes, int n_in,
                              void* d_out, int out_size, void* d_ws, size_t ws_size,
                              hipStream_t stream) {
  const float* x      = (const float*)d_in[0];
  const float* w_qkv  = (const float*)d_in[1];
  const float* b_qkv  = (const float*)d_in[2];
  const float* w_proj = (const float*)d_in[3];
  const float* b_proj = (const float*)d_in[4];
  float* out = (float*)d_out;

  u16* ws     = (u16*)d_ws;
  u16* x_bf   = ws;                                  // 4M u16; dead after QKV GEMM -> po1
  u16* wqkvT  = x_bf   + (size_t)MROWS * KD;         // 3M; dead after QKV GEMM -> l bufs
  u16* wprojT = wqkvT  + (size_t)NQKV * KD;          // 1M (kept for proj GEMM)
  u16* qkv    = wprojT + (size_t)DD * KD;            // 12M (V region unused)
  u16* attn   = qkv    + (size_t)MROWS * NQKV;       // 4M; doubles as po0
  u16* vt     = attn   + (size_t)MROWS * DD;         // 4M

  float* l0 = (float*)wqkvT;                         // 256 KB
  float* l1 = l0 + (size_t)2 * HH * SS;              // 256 KB

  k_prep<<<3072, 256, 0, stream>>>(x, w_qkv, w_proj, x_bf, wqkvT, wprojT);
  k_gemm<2, 128><<<dim3(NQKV / 128, MROWS / 128), 256, 0, stream>>>(x_bf, wqkvT, b_qkv, qkv, vt, MROWS, NQKV, KD);
  k_attn<<<2 * 2 * HH * (SS / 128), 256, 0, stream>>>(qkv, vt, attn, x_bf, l0, l1);
  k_comb<<<(MROWS * DD) / (256 * 8), 256, 0, stream>>>(attn, x_bf, l0, l1);
  k_gemm<0, 64><<<dim3(DD / 128, MROWS / 64), 256, 0, stream>>>(attn, wprojT, b_proj, out, nullptr, MROWS, DD, KD);
}

// Round 8
// 186.324 us; speedup vs baseline: 1.1273x; 1.1273x over previous
//
#include <hip/hip_runtime.h>
#include <math.h>

#define SS 2048
#define DD 1024
#define HH 16
#define NQKV 3072
#define MROWS 4096
#define KD 1024

typedef __attribute__((ext_vector_type(8))) short bf16x8;
typedef __attribute__((ext_vector_type(8))) unsigned short us8;
typedef __attribute__((ext_vector_type(4))) float f32x4;
typedef unsigned short u16;
typedef unsigned int u32;

#define SCALE_C 0.18033688011112042f  // log2(e)/sqrt(64), folded into Q at GEMM epilogue

// async global->LDS, 16B per lane; LDS dst = wave-uniform base + lane*16
#define GLDS16(g, l) \
  __builtin_amdgcn_global_load_lds((const __attribute__((address_space(1))) u32*)(g), \
                                   (__attribute__((address_space(3))) u32*)(l), 16, 0, 0)

static __device__ __forceinline__ u16 f2bf(float f) {
  union { float f; u32 u; } v; v.f = f;
  u32 u = v.u;
  u += 0x7fffu + ((u >> 16) & 1u);   // RNE
  return (u16)(u >> 16);
}
static __device__ __forceinline__ u32 pk2(float a, float b) {      // RNE pack
  return (u32)f2bf(a) | ((u32)f2bf(b) << 16);
}
static __device__ __forceinline__ u32 pk2t(float a, float b) {     // truncating pack, 1 v_perm
  union { float f; u32 u; } ua, ub; ua.f = a; ub.f = b;
  return __builtin_amdgcn_perm(ub.u, ua.u, 0x07060302u);
}

// ---- merged prep: x convert (blocks 0..2047), w_qkv T (2048..2815), w_proj T (2816..3071) ----
__global__ __launch_bounds__(256) void k_prep(const float* __restrict__ x,
                                              const float* __restrict__ w_qkv,
                                              const float* __restrict__ w_proj,
                                              u16* __restrict__ x_bf,
                                              u16* __restrict__ wqkvT,
                                              u16* __restrict__ wprojT) {
  __shared__ float t[64][65];
  int bx = blockIdx.x;
  int tid = threadIdx.x;
  if (bx < 2048) {
    int i = (bx * 256 + tid) * 8;
    float4 a = *(const float4*)(x + i);
    float4 b = *(const float4*)(x + i + 4);
    us8 o;
    o[0] = f2bf(a.x); o[1] = f2bf(a.y); o[2] = f2bf(a.z); o[3] = f2bf(a.w);
    o[4] = f2bf(b.x); o[5] = f2bf(b.y); o[6] = f2bf(b.z); o[7] = f2bf(b.w);
    *(us8*)(x_bf + i) = o;
    return;
  }
  const float* in; u16* out; int R = KD, C, tile;
  if (bx < 2048 + 768) { in = w_qkv; out = wqkvT; C = NQKV; tile = bx - 2048; }
  else                 { in = w_proj; out = wprojT; C = DD; tile = bx - 2816; }
  int tilesC = C >> 6;
  int tc = tile % tilesC, tr = tile / tilesC;
  int r0 = tr * 64, c0 = tc * 64;
  int lx = tid & 63, ly = tid >> 6;
#pragma unroll
  for (int i = 0; i < 16; i++) {
    int rr = ly + i * 4;
    t[rr][lx] = in[(size_t)(r0 + rr) * C + c0 + lx];
  }
  __syncthreads();
#pragma unroll
  for (int i = 0; i < 16; i++) {
    int cc = ly + i * 4;
    out[(size_t)(c0 + cc) * R + r0 + lx] = f2bf(t[lx][cc]);
  }
}

// ---- bf16 GEMM, BK=64 (half the barriers of m97's BK=32), single-buffer 32KB LDS.
// MODE 0: f32 out. MODE 2 (BM=128): bf16 qkv out; Q cols (n<1024) pre-scaled by
// SCALE_C; V cols (n>=2048) written ONLY transposed to vt[(b*16+h)*64+d][s]. ----
template <int MODE, int BM>
__global__ __launch_bounds__(256, 2) void k_gemm(const u16* __restrict__ A,
                                                 const u16* __restrict__ Bt,
                                                 const float* __restrict__ bias,
                                                 void* __restrict__ Cout,
                                                 u16* __restrict__ vt,
                                                 int M, int N, int K) {
  constexpr int MT = BM / 32;                // row-subtiles per wave: 4 or 2
  __shared__ alignas(16) u16 As[BM * 64];    // rows 128B, XOR-swizzled 16B chunks
  __shared__ alignas(16) u16 Bs[128 * 64];
  const int tid = threadIdx.x;
  const int w = tid >> 6, ln = tid & 63;
  const int wm = w >> 1, wn = w & 1;
  const int lm = ln & 15, quad = ln >> 4;
  const int m0 = blockIdx.y * BM, n0 = blockIdx.x * 128;
  const int lr = ln >> 3, cc = ln & 7;
  const int cg = cc ^ lr;                    // chunk swizzle: stored chunk = real ^ (row&7)

  f32x4 acc[MT][4];
#pragma unroll
  for (int i = 0; i < MT; i++)
#pragma unroll
    for (int j = 0; j < 4; j++) acc[i][j] = (f32x4){0.f, 0.f, 0.f, 0.f};

  const u16* gA = A  + (size_t)(m0 + lr) * K + cg * 8;
  const u16* gB = Bt + (size_t)(n0 + lr) * K + cg * 8;

  for (int k0 = 0; k0 < K; k0 += 64) {
    // stage A (BM rows x 128B) + B (128 rows x 128B); 1KB (8 rows) per instr
#pragma unroll
    for (int ii = 0; ii < MT; ii++) {
      int i = w + 4 * ii;
      GLDS16(gA + (size_t)(8 * i) * K + k0, (char*)As + i * 1024);
    }
#pragma unroll
    for (int ii = 0; ii < 4; ii++) {
      int i = w + 4 * ii;
      GLDS16(gB + (size_t)(8 * i) * K + k0, (char*)Bs + i * 1024);
    }
    __syncthreads();
    bf16x8 af[MT][2], bfr[4][2];
#pragma unroll
    for (int t = 0; t < MT; t++)
#pragma unroll
      for (int kk = 0; kk < 2; kk++)
        af[t][kk] = *(const bf16x8*)((const char*)As + (wm * (MT * 16) + t * 16 + lm) * 128 +
                                     (((kk * 4 + quad) ^ (lm & 7)) * 16));
#pragma unroll
    for (int t = 0; t < 4; t++)
#pragma unroll
      for (int kk = 0; kk < 2; kk++)
        bfr[t][kk] = *(const bf16x8*)((const char*)Bs + (wn * 64 + t * 16 + lm) * 128 +
                                      (((kk * 4 + quad) ^ (lm & 7)) * 16));
#pragma unroll
    for (int kk = 0; kk < 2; kk++)
#pragma unroll
      for (int mt = 0; mt < MT; mt++)
#pragma unroll
        for (int nt = 0; nt < 4; nt++)
          acc[mt][nt] = __builtin_amdgcn_mfma_f32_16x16x32_bf16(af[mt][kk], bfr[nt][kk], acc[mt][nt], 0, 0, 0);
    __syncthreads();
  }

  float bv[4];
#pragma unroll
  for (int nt = 0; nt < 4; nt++) bv[nt] = bias[n0 + wn * 64 + nt * 16 + lm];

  if (MODE == 2 && n0 >= 2 * DD) {
    // V tile: write transposed to vt. All rows of this tile share b.
    int b = m0 >> 11;
    int s0 = (m0 & 2047) + wm * 64;
#pragma unroll
    for (int mt = 0; mt < MT; mt++) {
      int s = s0 + mt * 16 + quad * 4;
#pragma unroll
      for (int nt = 0; nt < 4; nt++) {
        int n = n0 + wn * 64 + nt * 16 + lm;
        int bh = b * HH + ((n - 2 * DD) >> 6);
        int d = n & 63;
        uint2 v;
        v.x = pk2(acc[mt][nt][0] + bv[nt], acc[mt][nt][1] + bv[nt]);
        v.y = pk2(acc[mt][nt][2] + bv[nt], acc[mt][nt][3] + bv[nt]);
        *(uint2*)&vt[(size_t)(bh * 64 + d) * SS + s] = v;
      }
    }
    return;
  }

  const float qs = (MODE == 2 && n0 < DD) ? SCALE_C : 1.0f;  // fold softmax scale into Q
#pragma unroll
  for (int mt = 0; mt < MT; mt++) {
#pragma unroll
    for (int r = 0; r < 4; r++) {
      int row = m0 + wm * (MT * 16) + mt * 16 + quad * 4 + r;
#pragma unroll
      for (int nt = 0; nt < 4; nt++) {
        int col = n0 + wn * 64 + nt * 16 + lm;
        float v = (acc[mt][nt][r] + bv[nt]) * qs;
        if (MODE == 2) ((u16*)Cout)[(size_t)row * N + col] = f2bf(v);
        else           ((float*)Cout)[(size_t)row * N + col] = v;
      }
    }
  }
}

// ---- flash attention (r4 structure): block = (b,h,128 q), 4 waves x 32 q, grid 512.
//      S^T orientation, exp2 direct on MFMA output, dbuf K/V, 1 barrier/tile.
//      r8: vf hoisted before softmax; P written for both qs2 then read (lgkm overlap);
//      Ps swizzled 128B rows. LDS 48 KB. ----
__global__ __launch_bounds__(256, 2) void k_attn(const u16* __restrict__ qkv,
                                                 const u16* __restrict__ vt,
                                                 u16* __restrict__ attn) {
  __shared__ alignas(16) u16 Ks[2][64 * 64];    // dbuf [key][d]   16 KB
  __shared__ alignas(16) u16 Vs[2][64 * 64];    // dbuf [d][key]   16 KB
  __shared__ alignas(16) u16 Ps[4 * 32 * 64];   // per-wave 32x128B swizzled, 16 KB

  const int tid = threadIdx.x;
  const int w = tid >> 6, ln = tid & 63;
  const int lm = ln & 15, quad = ln >> 4;
  const int bx = blockIdx.x;
  const int bh = bx >> 4;
  const int q0 = (bx & 15) * 128;
  const int b = bh >> 4, h = bh & 15;
  const size_t qkv_b = (size_t)b * SS * NQKV;
  const int hcol = h * 64;

  const int lr = ln >> 3, cc = ln & 7;
  const int cg = cc ^ lr;   // XOR-swizzled source chunk (row&7 == lr)

  // Q straight to registers: 4 x 16B per lane, once per block (already *SCALE_C)
  bf16x8 qf[2][2];
#pragma unroll
  for (int qs2 = 0; qs2 < 2; qs2++)
#pragma unroll
    for (int kk = 0; kk < 2; kk++)
      qf[qs2][kk] = *(const bf16x8*)(qkv + qkv_b +
                     (size_t)(q0 + w * 32 + qs2 * 16 + lm) * NQKV + hcol + kk * 32 + quad * 8);

  f32x4 o[4][2];
  float l[2] = {0.f, 0.f};
#pragma unroll
  for (int t = 0; t < 4; t++) { o[t][0] = (f32x4){0, 0, 0, 0}; o[t][1] = (f32x4){0, 0, 0, 0}; }

  char* psw = (char*)Ps + w * 4096;             // this wave's 32x128B region

  // stage K/V tile 0 into buf 0
#pragma unroll
  for (int rr = 0; rr < 2; rr++) {
    int i = w + 4 * rr;
    GLDS16(qkv + qkv_b + (size_t)(8 * i + lr) * NQKV + DD + hcol + cg * 8, (char*)Ks[0] + i * 1024);
    GLDS16(vt + (size_t)(bh * 64 + 8 * i + lr) * SS + cg * 8,              (char*)Vs[0] + i * 1024);
  }

#pragma unroll 1
  for (int it = 0; it < SS / 64; it++) {
    __syncthreads();   // drains tile-it loads (issued one compute-phase ago)

    if (it + 1 < SS / 64) {
      int kv1 = (it + 1) * 64;
      char* kd = (char*)Ks[(it + 1) & 1];
      char* vd = (char*)Vs[(it + 1) & 1];
#pragma unroll
      for (int rr = 0; rr < 2; rr++) {
        int i = w + 4 * rr;
        GLDS16(qkv + qkv_b + (size_t)(kv1 + 8 * i + lr) * NQKV + DD + hcol + cg * 8, kd + i * 1024);
        GLDS16(vt + (size_t)(bh * 64 + 8 * i + lr) * SS + kv1 + cg * 8,              vd + i * 1024);
      }
    }

    const char* ksb = (const char*)Ks[it & 1];
    const char* vsb = (const char*)Vs[it & 1];

    // S^T = K · Q^T  (C: col = q = lane&15, row = key = quad*4+r (+16t))
    f32x4 s[4][2];
#pragma unroll
    for (int t = 0; t < 4; t++) { s[t][0] = (f32x4){0, 0, 0, 0}; s[t][1] = (f32x4){0, 0, 0, 0}; }
#pragma unroll
    for (int kk = 0; kk < 2; kk++)
#pragma unroll
      for (int t = 0; t < 4; t++) {
        bf16x8 kf = *(const bf16x8*)(ksb + (t * 16 + lm) * 128 + (((kk * 4 + quad) ^ (lm & 7)) * 16));
        s[t][0] = __builtin_amdgcn_mfma_f32_16x16x32_bf16(kf, qf[0][kk], s[t][0], 0, 0, 0);
        s[t][1] = __builtin_amdgcn_mfma_f32_16x16x32_bf16(kf, qf[1][kk], s[t][1], 0, 0, 0);
      }

    // V fragments hoisted: ds_reads proceed while exp2 runs
    bf16x8 vf[2][4];
#pragma unroll
    for (int kk = 0; kk < 2; kk++)
#pragma unroll
      for (int t = 0; t < 4; t++)
        vf[kk][t] = *(const bf16x8*)(vsb + (t * 16 + lm) * 128 + (((kk * 4 + quad) ^ (lm & 7)) * 16));

    // softmax numerators for BOTH qs2, write both P blocks to LDS
#pragma unroll
    for (int qs2 = 0; qs2 < 2; qs2++) {
      float sum = 0.f;
      u32 pkv[4][2];
#pragma unroll
      for (int t = 0; t < 4; t++) {
        float p0 = __builtin_amdgcn_exp2f(s[t][qs2][0]);
        float p1 = __builtin_amdgcn_exp2f(s[t][qs2][1]);
        float p2 = __builtin_amdgcn_exp2f(s[t][qs2][2]);
        float p3 = __builtin_amdgcn_exp2f(s[t][qs2][3]);
        sum += (p0 + p1) + (p2 + p3);
        pkv[t][0] = pk2t(p0, p1);
        pkv[t][1] = pk2t(p2, p3);
      }
      sum += __shfl_xor(sum, 16);
      sum += __shfl_xor(sum, 32);
      l[qs2] += sum;
      // keys t*16+quad*4+{0..3} at row qs2*16+lm: unswizzled byte off 32t+8*quad
#pragma unroll
      for (int t = 0; t < 4; t++) {
        uint2 v; v.x = pkv[t][0]; v.y = pkv[t][1];
        *(uint2*)(psw + (qs2 * 16 + lm) * 128 +
                  (((2 * t + (quad >> 1)) ^ (lm & 7)) * 16) + (quad & 1) * 8) = v;
      }
    }

    // read both P fragment sets, then all PV MFMAs (compiler overlaps via lgkmcnt)
    bf16x8 pf[2][2];
#pragma unroll
    for (int qs2 = 0; qs2 < 2; qs2++)
#pragma unroll
      for (int kk = 0; kk < 2; kk++)
        pf[qs2][kk] = *(const bf16x8*)(psw + (qs2 * 16 + lm) * 128 +
                                       (((kk * 4 + quad) ^ (lm & 7)) * 16));
#pragma unroll
    for (int kk = 0; kk < 2; kk++)
#pragma unroll
      for (int t = 0; t < 4; t++) {
        o[t][0] = __builtin_amdgcn_mfma_f32_16x16x32_bf16(vf[kk][t], pf[0][kk], o[t][0], 0, 0, 0);
        o[t][1] = __builtin_amdgcn_mfma_f32_16x16x32_bf16(vf[kk][t], pf[1][kk], o[t][1], 0, 0, 0);
      }
  }

  // normalize + store (O^T: col = q = lm; rows d = quad*4+r)
#pragma unroll
  for (int qs2 = 0; qs2 < 2; qs2++) {
    float il = 1.0f / l[qs2];
    int row = b * SS + q0 + w * 32 + qs2 * 16 + lm;
#pragma unroll
    for (int t = 0; t < 4; t++) {
      uint2 v;
      v.x = pk2(o[t][qs2][0] * il, o[t][qs2][1] * il);
      v.y = pk2(o[t][qs2][2] * il, o[t][qs2][3] * il);
      *(uint2*)&attn[(size_t)row * DD + hcol + t * 16 + quad * 4] = v;
    }
  }
}

extern "C" void kernel_launch(void* const* d_in, const int* in_sizes, int n_in,
                              void* d_out, int out_size, void* d_ws, size_t ws_size,
                              hipStream_t stream) {
  const float* x      = (const float*)d_in[0];
  const float* w_qkv  = (const float*)d_in[1];
  const float* b_qkv  = (const float*)d_in[2];
  const float* w_proj = (const float*)d_in[3];
  const float* b_proj = (const float*)d_in[4];
  float* out = (float*)d_out;

  u16* ws     = (u16*)d_ws;
  u16* x_bf   = ws;                                  // 4M u16
  u16* wqkvT  = x_bf   + (size_t)MROWS * KD;         // 3M
  u16* wprojT = wqkvT  + (size_t)NQKV * KD;          // 1M
  u16* qkv    = wprojT + (size_t)DD * KD;            // 12M (V region unused)
  u16* attn   = qkv    + (size_t)MROWS * NQKV;       // 4M
  u16* vt     = attn   + (size_t)MROWS * DD;         // 4M

  k_prep<<<3072, 256, 0, stream>>>(x, w_qkv, w_proj, x_bf, wqkvT, wprojT);
  k_gemm<2, 128><<<dim3(NQKV / 128, MROWS / 128), 256, 0, stream>>>(x_bf, wqkvT, b_qkv, qkv, vt, MROWS, NQKV, KD);
  k_attn<<<2 * HH * (SS / 128), 256, 0, stream>>>(qkv, vt, attn);
  k_gemm<0, 64><<<dim3(DD / 128, MROWS / 64), 256, 0, stream>>>(attn, wprojT, b_proj, out, nullptr, MROWS, DD, KD);
}

// Round 9
// 176.974 us; speedup vs baseline: 1.1868x; 1.0528x over previous
//
#include <hip/hip_runtime.h>
#include <math.h>

#define SS 2048
#define DD 1024
#define HH 16
#define NQKV 3072
#define MROWS 4096
#define KD 1024

typedef __attribute__((ext_vector_type(8))) short bf16x8;
typedef __attribute__((ext_vector_type(8))) unsigned short us8;
typedef __attribute__((ext_vector_type(4))) float f32x4;
typedef unsigned short u16;
typedef unsigned int u32;

#define SCALE_C 0.18033688011112042f  // log2(e)/sqrt(64), folded into Q at GEMM epilogue

// async global->LDS, 16B per lane; LDS dst = wave-uniform base + lane*16
#define GLDS16(g, l) \
  __builtin_amdgcn_global_load_lds((const __attribute__((address_space(1))) u32*)(g), \
                                   (__attribute__((address_space(3))) u32*)(l), 16, 0, 0)

static __device__ __forceinline__ u16 f2bf(float f) {
  union { float f; u32 u; } v; v.f = f;
  u32 u = v.u;
  u += 0x7fffu + ((u >> 16) & 1u);   // RNE
  return (u16)(u >> 16);
}
static __device__ __forceinline__ u32 pk2(float a, float b) {      // RNE pack
  return (u32)f2bf(a) | ((u32)f2bf(b) << 16);
}
static __device__ __forceinline__ u32 pk2t(float a, float b) {     // truncating pack, 1 v_perm
  union { float f; u32 u; } ua, ub; ua.f = a; ub.f = b;
  return __builtin_amdgcn_perm(ub.u, ua.u, 0x07060302u);
}

// ---- merged prep: x convert (blocks 0..2047), w_qkv T (2048..2815), w_proj T (2816..3071) ----
__global__ __launch_bounds__(256) void k_prep(const float* __restrict__ x,
                                              const float* __restrict__ w_qkv,
                                              const float* __restrict__ w_proj,
                                              u16* __restrict__ x_bf,
                                              u16* __restrict__ wqkvT,
                                              u16* __restrict__ wprojT) {
  __shared__ float t[64][65];
  int bx = blockIdx.x;
  int tid = threadIdx.x;
  if (bx < 2048) {
    int i = (bx * 256 + tid) * 8;
    float4 a = *(const float4*)(x + i);
    float4 b = *(const float4*)(x + i + 4);
    us8 o;
    o[0] = f2bf(a.x); o[1] = f2bf(a.y); o[2] = f2bf(a.z); o[3] = f2bf(a.w);
    o[4] = f2bf(b.x); o[5] = f2bf(b.y); o[6] = f2bf(b.z); o[7] = f2bf(b.w);
    *(us8*)(x_bf + i) = o;
    return;
  }
  const float* in; u16* out; int R = KD, C, tile;
  if (bx < 2048 + 768) { in = w_qkv; out = wqkvT; C = NQKV; tile = bx - 2048; }
  else                 { in = w_proj; out = wprojT; C = DD; tile = bx - 2816; }
  int tilesC = C >> 6;
  int tc = tile % tilesC, tr = tile / tilesC;
  int r0 = tr * 64, c0 = tc * 64;
  int lx = tid & 63, ly = tid >> 6;
#pragma unroll
  for (int i = 0; i < 16; i++) {
    int rr = ly + i * 4;
    t[rr][lx] = in[(size_t)(r0 + rr) * C + c0 + lx];
  }
  __syncthreads();
#pragma unroll
  for (int i = 0; i < 16; i++) {
    int cc = ly + i * 4;
    out[(size_t)(c0 + cc) * R + r0 + lx] = f2bf(t[lx][cc]);
  }
}

// ---- bf16 GEMM, BK=64, single-buffer 32KB LDS (r8-verified).
// MODE 0: f32 out. MODE 2 (BM=128): bf16 qkv out; Q cols (n<1024) pre-scaled by
// SCALE_C; V cols (n>=2048) written ONLY transposed to vt[(b*16+h)*64+d][s]. ----
template <int MODE, int BM>
__global__ __launch_bounds__(256, 2) void k_gemm(const u16* __restrict__ A,
                                                 const u16* __restrict__ Bt,
                                                 const float* __restrict__ bias,
                                                 void* __restrict__ Cout,
                                                 u16* __restrict__ vt,
                                                 int M, int N, int K) {
  constexpr int MT = BM / 32;                // row-subtiles per wave: 4 or 2
  __shared__ alignas(16) u16 As[BM * 64];    // rows 128B, XOR-swizzled 16B chunks
  __shared__ alignas(16) u16 Bs[128 * 64];
  const int tid = threadIdx.x;
  const int w = tid >> 6, ln = tid & 63;
  const int wm = w >> 1, wn = w & 1;
  const int lm = ln & 15, quad = ln >> 4;
  const int m0 = blockIdx.y * BM, n0 = blockIdx.x * 128;
  const int lr = ln >> 3, cc = ln & 7;
  const int cg = cc ^ lr;                    // chunk swizzle: stored chunk = real ^ (row&7)

  f32x4 acc[MT][4];
#pragma unroll
  for (int i = 0; i < MT; i++)
#pragma unroll
    for (int j = 0; j < 4; j++) acc[i][j] = (f32x4){0.f, 0.f, 0.f, 0.f};

  const u16* gA = A  + (size_t)(m0 + lr) * K + cg * 8;
  const u16* gB = Bt + (size_t)(n0 + lr) * K + cg * 8;

  for (int k0 = 0; k0 < K; k0 += 64) {
    // stage A (BM rows x 128B) + B (128 rows x 128B); 1KB (8 rows) per instr
#pragma unroll
    for (int ii = 0; ii < MT; ii++) {
      int i = w + 4 * ii;
      GLDS16(gA + (size_t)(8 * i) * K + k0, (char*)As + i * 1024);
    }
#pragma unroll
    for (int ii = 0; ii < 4; ii++) {
      int i = w + 4 * ii;
      GLDS16(gB + (size_t)(8 * i) * K + k0, (char*)Bs + i * 1024);
    }
    __syncthreads();
    bf16x8 af[MT][2], bfr[4][2];
#pragma unroll
    for (int t = 0; t < MT; t++)
#pragma unroll
      for (int kk = 0; kk < 2; kk++)
        af[t][kk] = *(const bf16x8*)((const char*)As + (wm * (MT * 16) + t * 16 + lm) * 128 +
                                     (((kk * 4 + quad) ^ (lm & 7)) * 16));
#pragma unroll
    for (int t = 0; t < 4; t++)
#pragma unroll
      for (int kk = 0; kk < 2; kk++)
        bfr[t][kk] = *(const bf16x8*)((const char*)Bs + (wn * 64 + t * 16 + lm) * 128 +
                                      (((kk * 4 + quad) ^ (lm & 7)) * 16));
#pragma unroll
    for (int kk = 0; kk < 2; kk++)
#pragma unroll
      for (int mt = 0; mt < MT; mt++)
#pragma unroll
        for (int nt = 0; nt < 4; nt++)
          acc[mt][nt] = __builtin_amdgcn_mfma_f32_16x16x32_bf16(af[mt][kk], bfr[nt][kk], acc[mt][nt], 0, 0, 0);
    __syncthreads();
  }

  float bv[4];
#pragma unroll
  for (int nt = 0; nt < 4; nt++) bv[nt] = bias[n0 + wn * 64 + nt * 16 + lm];

  if (MODE == 2 && n0 >= 2 * DD) {
    // V tile: write transposed to vt. All rows of this tile share b.
    int b = m0 >> 11;
    int s0 = (m0 & 2047) + wm * 64;
#pragma unroll
    for (int mt = 0; mt < MT; mt++) {
      int s = s0 + mt * 16 + quad * 4;
#pragma unroll
      for (int nt = 0; nt < 4; nt++) {
        int n = n0 + wn * 64 + nt * 16 + lm;
        int bh = b * HH + ((n - 2 * DD) >> 6);
        int d = n & 63;
        uint2 v;
        v.x = pk2(acc[mt][nt][0] + bv[nt], acc[mt][nt][1] + bv[nt]);
        v.y = pk2(acc[mt][nt][2] + bv[nt], acc[mt][nt][3] + bv[nt]);
        *(uint2*)&vt[(size_t)(bh * 64 + d) * SS + s] = v;
      }
    }
    return;
  }

  const float qs = (MODE == 2 && n0 < DD) ? SCALE_C : 1.0f;  // fold softmax scale into Q
#pragma unroll
  for (int mt = 0; mt < MT; mt++) {
#pragma unroll
    for (int r = 0; r < 4; r++) {
      int row = m0 + wm * (MT * 16) + mt * 16 + quad * 4 + r;
#pragma unroll
      for (int nt = 0; nt < 4; nt++) {
        int col = n0 + wn * 64 + nt * 16 + lm;
        float v = (acc[mt][nt][r] + bv[nt]) * qs;
        if (MODE == 2) ((u16*)Cout)[(size_t)row * N + col] = f2bf(v);
        else           ((float*)Cout)[(size_t)row * N + col] = v;
      }
    }
  }
}

// ---- flash attention: block = (b,h,128 q), 4 waves x 32 q, grid 512.
//      r9: 128-key K/V tiles (half the barriers of r8), dbuf; inner 64-key halves
//      reuse the 16KB Ps scratch (per-wave DS order). LDS 80 KB -> 2 blocks/CU. ----
__global__ __launch_bounds__(256, 2) void k_attn(const u16* __restrict__ qkv,
                                                 const u16* __restrict__ vt,
                                                 u16* __restrict__ attn) {
  __shared__ alignas(16) u16 Ks[2][128 * 64];   // dbuf [key][d], 128B rows   16 KB each
  __shared__ alignas(16) u16 Vs[2][64 * 128];   // dbuf [d][key], 256B rows   16 KB each
  __shared__ alignas(16) u16 Ps[4 * 32 * 64];   // per-wave 32x128B swizzled, 16 KB

  const int tid = threadIdx.x;
  const int w = tid >> 6, ln = tid & 63;
  const int lm = ln & 15, quad = ln >> 4;
  const int bx = blockIdx.x;
  const int bh = bx >> 4;
  const int q0 = (bx & 15) * 128;
  const int b = bh >> 4, h = bh & 15;
  const size_t qkv_b = (size_t)b * SS * NQKV;
  const int hcol = h * 64;

  const int lr = ln >> 3, cc = ln & 7;
  const int cg = cc ^ lr;          // K-staging chunk swizzle (8 chunks, row&7 == lr)
  const int vr = ln >> 4, c16 = ln & 15;   // V-staging: 4 rows x 16 chunks per 1KB instr

  // Q straight to registers: 4 x 16B per lane, once per block (already *SCALE_C)
  bf16x8 qf[2][2];
#pragma unroll
  for (int qs2 = 0; qs2 < 2; qs2++)
#pragma unroll
    for (int kk = 0; kk < 2; kk++)
      qf[qs2][kk] = *(const bf16x8*)(qkv + qkv_b +
                     (size_t)(q0 + w * 32 + qs2 * 16 + lm) * NQKV + hcol + kk * 32 + quad * 8);

  f32x4 o[4][2];
  float l[2] = {0.f, 0.f};
#pragma unroll
  for (int t = 0; t < 4; t++) { o[t][0] = (f32x4){0, 0, 0, 0}; o[t][1] = (f32x4){0, 0, 0, 0}; }

  char* psw = (char*)Ps + w * 4096;             // this wave's 32x128B region

  // stage K/V tile 0 (128 keys) into buf 0: 16 x 1KB each of K and V
#pragma unroll
  for (int rr = 0; rr < 4; rr++) {
    int i = w + 4 * rr;
    GLDS16(qkv + qkv_b + (size_t)(8 * i + lr) * NQKV + DD + hcol + cg * 8, (char*)Ks[0] + i * 1024);
    int cgv = c16 ^ ((4 * i + vr) & 15);
    GLDS16(vt + (size_t)(bh * 64 + 4 * i + vr) * SS + cgv * 8,             (char*)Vs[0] + i * 1024);
  }

#pragma unroll 1
  for (int it = 0; it < SS / 128; it++) {
    __syncthreads();   // drains tile-it loads (issued one compute-phase ago)

    if (it + 1 < SS / 128) {
      int kv1 = (it + 1) * 128;
      char* kd = (char*)Ks[(it + 1) & 1];
      char* vd = (char*)Vs[(it + 1) & 1];
#pragma unroll
      for (int rr = 0; rr < 4; rr++) {
        int i = w + 4 * rr;
        GLDS16(qkv + qkv_b + (size_t)(kv1 + 8 * i + lr) * NQKV + DD + hcol + cg * 8, kd + i * 1024);
        int cgv = c16 ^ ((4 * i + vr) & 15);
        GLDS16(vt + (size_t)(bh * 64 + 4 * i + vr) * SS + kv1 + cgv * 8,             vd + i * 1024);
      }
    }

    const char* ksb = (const char*)Ks[it & 1];
    const char* vsb = (const char*)Vs[it & 1];

    // two 64-key halves per staged tile; Ps scratch reused (per-wave DS order)
#pragma unroll
    for (int sub = 0; sub < 2; sub++) {
      // S^T = K · Q^T  (C: col = q = lane&15, row = key = quad*4+r (+16t))
      f32x4 s[4][2];
#pragma unroll
      for (int t = 0; t < 4; t++) { s[t][0] = (f32x4){0, 0, 0, 0}; s[t][1] = (f32x4){0, 0, 0, 0}; }
#pragma unroll
      for (int kk = 0; kk < 2; kk++)
#pragma unroll
        for (int t = 0; t < 4; t++) {
          bf16x8 kf = *(const bf16x8*)(ksb + (sub * 64 + t * 16 + lm) * 128 +
                                       (((kk * 4 + quad) ^ (lm & 7)) * 16));
          s[t][0] = __builtin_amdgcn_mfma_f32_16x16x32_bf16(kf, qf[0][kk], s[t][0], 0, 0, 0);
          s[t][1] = __builtin_amdgcn_mfma_f32_16x16x32_bf16(kf, qf[1][kk], s[t][1], 0, 0, 0);
        }

      // V fragments hoisted: ds_reads proceed while exp2 runs
      bf16x8 vf[2][4];
#pragma unroll
      for (int kk = 0; kk < 2; kk++)
#pragma unroll
        for (int t = 0; t < 4; t++)
          vf[kk][t] = *(const bf16x8*)(vsb + (t * 16 + lm) * 256 +
                                       (((sub * 8 + kk * 4 + quad) ^ lm) * 16));

      // softmax numerators for BOTH qs2, write both P blocks to LDS
#pragma unroll
      for (int qs2 = 0; qs2 < 2; qs2++) {
        float sum = 0.f;
        u32 pkv[4][2];
#pragma unroll
        for (int t = 0; t < 4; t++) {
          float p0 = __builtin_amdgcn_exp2f(s[t][qs2][0]);
          float p1 = __builtin_amdgcn_exp2f(s[t][qs2][1]);
          float p2 = __builtin_amdgcn_exp2f(s[t][qs2][2]);
          float p3 = __builtin_amdgcn_exp2f(s[t][qs2][3]);
          sum += (p0 + p1) + (p2 + p3);
          pkv[t][0] = pk2t(p0, p1);
          pkv[t][1] = pk2t(p2, p3);
        }
        sum += __shfl_xor(sum, 16);
        sum += __shfl_xor(sum, 32);
        l[qs2] += sum;
        // keys t*16+quad*4+{0..3} at row qs2*16+lm: unswizzled byte off 32t+8*quad
#pragma unroll
        for (int t = 0; t < 4; t++) {
          uint2 v; v.x = pkv[t][0]; v.y = pkv[t][1];
          *(uint2*)(psw + (qs2 * 16 + lm) * 128 +
                    (((2 * t + (quad >> 1)) ^ (lm & 7)) * 16) + (quad & 1) * 8) = v;
        }
      }

      // read both P fragment sets, then all PV MFMAs (compiler overlaps via lgkmcnt)
      bf16x8 pf[2][2];
#pragma unroll
      for (int qs2 = 0; qs2 < 2; qs2++)
#pragma unroll
        for (int kk = 0; kk < 2; kk++)
          pf[qs2][kk] = *(const bf16x8*)(psw + (qs2 * 16 + lm) * 128 +
                                         (((kk * 4 + quad) ^ (lm & 7)) * 16));
#pragma unroll
      for (int kk = 0; kk < 2; kk++)
#pragma unroll
        for (int t = 0; t < 4; t++) {
          o[t][0] = __builtin_amdgcn_mfma_f32_16x16x32_bf16(vf[kk][t], pf[0][kk], o[t][0], 0, 0, 0);
          o[t][1] = __builtin_amdgcn_mfma_f32_16x16x32_bf16(vf[kk][t], pf[1][kk], o[t][1], 0, 0, 0);
        }
    }
  }

  // normalize + store (O^T: col = q = lm; rows d = quad*4+r)
#pragma unroll
  for (int qs2 = 0; qs2 < 2; qs2++) {
    float il = 1.0f / l[qs2];
    int row = b * SS + q0 + w * 32 + qs2 * 16 + lm;
#pragma unroll
    for (int t = 0; t < 4; t++) {
      uint2 v;
      v.x = pk2(o[t][qs2][0] * il, o[t][qs2][1] * il);
      v.y = pk2(o[t][qs2][2] * il, o[t][qs2][3] * il);
      *(uint2*)&attn[(size_t)row * DD + hcol + t * 16 + quad * 4] = v;
    }
  }
}

extern "C" void kernel_launch(void* const* d_in, const int* in_sizes, int n_in,
                              void* d_out, int out_size, void* d_ws, size_t ws_size,
                              hipStream_t stream) {
  const float* x      = (const float*)d_in[0];
  const float* w_qkv  = (const float*)d_in[1];
  const float* b_qkv  = (const float*)d_in[2];
  const float* w_proj = (const float*)d_in[3];
  const float* b_proj = (const float*)d_in[4];
  float* out = (float*)d_out;

  u16* ws     = (u16*)d_ws;
  u16* x_bf   = ws;                                  // 4M u16
  u16* wqkvT  = x_bf   + (size_t)MROWS * KD;         // 3M
  u16* wprojT = wqkvT  + (size_t)NQKV * KD;          // 1M
  u16* qkv    = wprojT + (size_t)DD * KD;            // 12M (V region unused)
  u16* attn   = qkv    + (size_t)MROWS * NQKV;       // 4M
  u16* vt     = attn   + (size_t)MROWS * DD;         // 4M

  k_prep<<<3072, 256, 0, stream>>>(x, w_qkv, w_proj, x_bf, wqkvT, wprojT);
  k_gemm<2, 128><<<dim3(NQKV / 128, MROWS / 128), 256, 0, stream>>>(x_bf, wqkvT, b_qkv, qkv, vt, MROWS, NQKV, KD);
  k_attn<<<2 * HH * (SS / 128), 256, 0, stream>>>(qkv, vt, attn);
  k_gemm<0, 64><<<dim3(DD / 128, MROWS / 64), 256, 0, stream>>>(attn, wprojT, b_proj, out, nullptr, MROWS, DD, KD);
}

// Round 10
// 176.436 us; speedup vs baseline: 1.1905x; 1.0030x over previous
//
#include <hip/hip_runtime.h>
#include <math.h>

#define SS 2048
#define DD 1024
#define HH 16
#define NQKV 3072
#define MROWS 4096
#define KD 1024

typedef __attribute__((ext_vector_type(8))) short bf16x8;
typedef __attribute__((ext_vector_type(8))) unsigned short us8;
typedef __attribute__((ext_vector_type(4))) float f32x4;
typedef __attribute__((ext_vector_type(16))) float f32x16;
typedef unsigned short u16;
typedef unsigned int u32;

#define SCALE_C 0.18033688011112042f  // log2(e)/sqrt(64), folded into Q at GEMM epilogue

// async global->LDS, 16B per lane; LDS dst = wave-uniform base + lane*16
#define GLDS16(g, l) \
  __builtin_amdgcn_global_load_lds((const __attribute__((address_space(1))) u32*)(g), \
                                   (__attribute__((address_space(3))) u32*)(l), 16, 0, 0)

static __device__ __forceinline__ u16 f2bf(float f) {
  union { float f; u32 u; } v; v.f = f;
  u32 u = v.u;
  u += 0x7fffu + ((u >> 16) & 1u);   // RNE
  return (u16)(u >> 16);
}
static __device__ __forceinline__ u32 pk2(float a, float b) {      // RNE pack
  return (u32)f2bf(a) | ((u32)f2bf(b) << 16);
}
static __device__ __forceinline__ u32 pk2t(float a, float b) {     // truncating pack, 1 v_perm
  union { float f; u32 u; } ua, ub; ua.f = a; ub.f = b;
  return __builtin_amdgcn_perm(ub.u, ua.u, 0x07060302u);
}

// ---- merged prep: x convert (blocks 0..2047), w_qkv T (2048..2815), w_proj T (2816..3071) ----
__global__ __launch_bounds__(256) void k_prep(const float* __restrict__ x,
                                              const float* __restrict__ w_qkv,
                                              const float* __restrict__ w_proj,
                                              u16* __restrict__ x_bf,
                                              u16* __restrict__ wqkvT,
                                              u16* __restrict__ wprojT) {
  __shared__ float t[64][65];
  int bx = blockIdx.x;
  int tid = threadIdx.x;
  if (bx < 2048) {
    int i = (bx * 256 + tid) * 8;
    float4 a = *(const float4*)(x + i);
    float4 b = *(const float4*)(x + i + 4);
    us8 o;
    o[0] = f2bf(a.x); o[1] = f2bf(a.y); o[2] = f2bf(a.z); o[3] = f2bf(a.w);
    o[4] = f2bf(b.x); o[5] = f2bf(b.y); o[6] = f2bf(b.z); o[7] = f2bf(b.w);
    *(us8*)(x_bf + i) = o;
    return;
  }
  const float* in; u16* out; int R = KD, C, tile;
  if (bx < 2048 + 768) { in = w_qkv; out = wqkvT; C = NQKV; tile = bx - 2048; }
  else                 { in = w_proj; out = wprojT; C = DD; tile = bx - 2816; }
  int tilesC = C >> 6;
  int tc = tile % tilesC, tr = tile / tilesC;
  int r0 = tr * 64, c0 = tc * 64;
  int lx = tid & 63, ly = tid >> 6;
#pragma unroll
  for (int i = 0; i < 16; i++) {
    int rr = ly + i * 4;
    t[rr][lx] = in[(size_t)(r0 + rr) * C + c0 + lx];
  }
  __syncthreads();
#pragma unroll
  for (int i = 0; i < 16; i++) {
    int cc = ly + i * 4;
    out[(size_t)(c0 + cc) * R + r0 + lx] = f2bf(t[lx][cc]);
  }
}

// ---- bf16 GEMM, BK=64, single-buffer 32KB LDS (r8/r9-verified, unchanged).
// MODE 0: f32 out. MODE 2 (BM=128): bf16 qkv out; Q cols (n<1024) pre-scaled by
// SCALE_C; V cols (n>=2048) written ONLY transposed to vt[(b*16+h)*64+d][s]. ----
template <int MODE, int BM>
__global__ __launch_bounds__(256, 2) void k_gemm(const u16* __restrict__ A,
                                                 const u16* __restrict__ Bt,
                                                 const float* __restrict__ bias,
                                                 void* __restrict__ Cout,
                                                 u16* __restrict__ vt,
                                                 int M, int N, int K) {
  constexpr int MT = BM / 32;                // row-subtiles per wave: 4 or 2
  __shared__ alignas(16) u16 As[BM * 64];    // rows 128B, XOR-swizzled 16B chunks
  __shared__ alignas(16) u16 Bs[128 * 64];
  const int tid = threadIdx.x;
  const int w = tid >> 6, ln = tid & 63;
  const int wm = w >> 1, wn = w & 1;
  const int lm = ln & 15, quad = ln >> 4;
  const int m0 = blockIdx.y * BM, n0 = blockIdx.x * 128;
  const int lr = ln >> 3, cc = ln & 7;
  const int cg = cc ^ lr;                    // chunk swizzle: stored chunk = real ^ (row&7)

  f32x4 acc[MT][4];
#pragma unroll
  for (int i = 0; i < MT; i++)
#pragma unroll
    for (int j = 0; j < 4; j++) acc[i][j] = (f32x4){0.f, 0.f, 0.f, 0.f};

  const u16* gA = A  + (size_t)(m0 + lr) * K + cg * 8;
  const u16* gB = Bt + (size_t)(n0 + lr) * K + cg * 8;

  for (int k0 = 0; k0 < K; k0 += 64) {
    // stage A (BM rows x 128B) + B (128 rows x 128B); 1KB (8 rows) per instr
#pragma unroll
    for (int ii = 0; ii < MT; ii++) {
      int i = w + 4 * ii;
      GLDS16(gA + (size_t)(8 * i) * K + k0, (char*)As + i * 1024);
    }
#pragma unroll
    for (int ii = 0; ii < 4; ii++) {
      int i = w + 4 * ii;
      GLDS16(gB + (size_t)(8 * i) * K + k0, (char*)Bs + i * 1024);
    }
    __syncthreads();
    bf16x8 af[MT][2], bfr[4][2];
#pragma unroll
    for (int t = 0; t < MT; t++)
#pragma unroll
      for (int kk = 0; kk < 2; kk++)
        af[t][kk] = *(const bf16x8*)((const char*)As + (wm * (MT * 16) + t * 16 + lm) * 128 +
                                     (((kk * 4 + quad) ^ (lm & 7)) * 16));
#pragma unroll
    for (int t = 0; t < 4; t++)
#pragma unroll
      for (int kk = 0; kk < 2; kk++)
        bfr[t][kk] = *(const bf16x8*)((const char*)Bs + (wn * 64 + t * 16 + lm) * 128 +
                                      (((kk * 4 + quad) ^ (lm & 7)) * 16));
#pragma unroll
    for (int kk = 0; kk < 2; kk++)
#pragma unroll
      for (int mt = 0; mt < MT; mt++)
#pragma unroll
        for (int nt = 0; nt < 4; nt++)
          acc[mt][nt] = __builtin_amdgcn_mfma_f32_16x16x32_bf16(af[mt][kk], bfr[nt][kk], acc[mt][nt], 0, 0, 0);
    __syncthreads();
  }

  float bv[4];
#pragma unroll
  for (int nt = 0; nt < 4; nt++) bv[nt] = bias[n0 + wn * 64 + nt * 16 + lm];

  if (MODE == 2 && n0 >= 2 * DD) {
    // V tile: write transposed to vt. All rows of this tile share b.
    int b = m0 >> 11;
    int s0 = (m0 & 2047) + wm * 64;
#pragma unroll
    for (int mt = 0; mt < MT; mt++) {
      int s = s0 + mt * 16 + quad * 4;
#pragma unroll
      for (int nt = 0; nt < 4; nt++) {
        int n = n0 + wn * 64 + nt * 16 + lm;
        int bh = b * HH + ((n - 2 * DD) >> 6);
        int d = n & 63;
        uint2 v;
        v.x = pk2(acc[mt][nt][0] + bv[nt], acc[mt][nt][1] + bv[nt]);
        v.y = pk2(acc[mt][nt][2] + bv[nt], acc[mt][nt][3] + bv[nt]);
        *(uint2*)&vt[(size_t)(bh * 64 + d) * SS + s] = v;
      }
    }
    return;
  }

  const float qs = (MODE == 2 && n0 < DD) ? SCALE_C : 1.0f;  // fold softmax scale into Q
#pragma unroll
  for (int mt = 0; mt < MT; mt++) {
#pragma unroll
    for (int r = 0; r < 4; r++) {
      int row = m0 + wm * (MT * 16) + mt * 16 + quad * 4 + r;
#pragma unroll
      for (int nt = 0; nt < 4; nt++) {
        int col = n0 + wn * 64 + nt * 16 + lm;
        float v = (acc[mt][nt][r] + bv[nt]) * qs;
        if (MODE == 2) ((u16*)Cout)[(size_t)row * N + col] = f2bf(v);
        else           ((float*)Cout)[(size_t)row * N + col] = v;
      }
    }
  }
}

// ---- flash attention, r10: 32x32x16 MFMA. Block = (b,h,128 q), 4 waves x 32 q,
//      grid 512; 128-key dbuf tiles (r9 staging unchanged). Each lane owns ONE q
//      (C col = lane&31): softmax fully lane-local, l reduced once at kernel end.
//      MFMA count halves vs r9; LDS bytes unchanged. 80 KB -> 2 blocks/CU. ----
__global__ __launch_bounds__(256, 2) void k_attn(const u16* __restrict__ qkv,
                                                 const u16* __restrict__ vt,
                                                 u16* __restrict__ attn) {
  __shared__ alignas(16) u16 Ks[2][128 * 64];   // dbuf [key][d], 128B rows
  __shared__ alignas(16) u16 Vs[2][64 * 128];   // dbuf [d][key], 256B rows
  __shared__ alignas(16) u16 Ps[4 * 32 * 64];   // per-wave 32 q-rows x 128B, swizzled

  const int tid = threadIdx.x;
  const int w = tid >> 6, ln = tid & 63;
  const int qn = ln & 31, h5 = ln >> 5;         // lane's q-index / k-half
  const int bx = blockIdx.x;
  const int bh = bx >> 4;
  const int q0 = (bx & 15) * 128;
  const int b = bh >> 4, h = bh & 15;
  const size_t qkv_b = (size_t)b * SS * NQKV;
  const int hcol = h * 64;

  const int lr = ln >> 3, cc = ln & 7;
  const int cg = cc ^ lr;                  // K-staging chunk swizzle (row&7)
  const int vr = ln >> 4, c16 = ln & 15;   // V-staging: 4 rows x 16 chunks per 1KB

  // Q B-fragments direct from global: B[k=d][n=q], d = 16*ks + 8*h5 + j
  bf16x8 qf[4];
  {
    const u16* qp = qkv + qkv_b + (size_t)(q0 + w * 32 + qn) * NQKV + hcol + h5 * 8;
#pragma unroll
    for (int ks = 0; ks < 4; ks++) qf[ks] = *(const bf16x8*)(qp + ks * 16);
  }

  f32x16 o[2];
#pragma unroll
  for (int i = 0; i < 16; i++) { o[0][i] = 0.f; o[1][i] = 0.f; }
  float lsum = 0.f;

  char* psw = (char*)Ps + w * 4096;             // this wave's 32x128B region

  // stage K/V tile 0 (128 keys) into buf 0: 16 x 1KB each of K and V
#pragma unroll
  for (int rr = 0; rr < 4; rr++) {
    int i = w + 4 * rr;
    GLDS16(qkv + qkv_b + (size_t)(8 * i + lr) * NQKV + DD + hcol + cg * 8, (char*)Ks[0] + i * 1024);
    int cgv = c16 ^ ((4 * i + vr) & 15);
    GLDS16(vt + (size_t)(bh * 64 + 4 * i + vr) * SS + cgv * 8,             (char*)Vs[0] + i * 1024);
  }

#pragma unroll 1
  for (int it = 0; it < SS / 128; it++) {
    __syncthreads();   // drains tile-it loads (issued one compute-phase ago)

    if (it + 1 < SS / 128) {
      int kv1 = (it + 1) * 128;
      char* kd = (char*)Ks[(it + 1) & 1];
      char* vd = (char*)Vs[(it + 1) & 1];
#pragma unroll
      for (int rr = 0; rr < 4; rr++) {
        int i = w + 4 * rr;
        GLDS16(qkv + qkv_b + (size_t)(kv1 + 8 * i + lr) * NQKV + DD + hcol + cg * 8, kd + i * 1024);
        int cgv = c16 ^ ((4 * i + vr) & 15);
        GLDS16(vt + (size_t)(bh * 64 + 4 * i + vr) * SS + kv1 + cgv * 8,             vd + i * 1024);
      }
    }

    const char* ksb = (const char*)Ks[it & 1];
    const char* vsb = (const char*)Vs[it & 1];

    // two 64-key halves per staged tile; Ps scratch reused (per-wave DS order)
#pragma unroll
    for (int sub = 0; sub < 2; sub++) {
      // S^T[key][q] = K · Q^T, two 32-key m-subtiles, 4 k-steps of 16 over d
      f32x16 s0, s1;
#pragma unroll
      for (int i = 0; i < 16; i++) { s0[i] = 0.f; s1[i] = 0.f; }
#pragma unroll
      for (int ks = 0; ks < 4; ks++) {
        int ch = 2 * ks + h5;
        bf16x8 kf0 = *(const bf16x8*)(ksb + (sub * 64 + qn) * 128 + ((ch ^ (qn & 7)) * 16));
        bf16x8 kf1 = *(const bf16x8*)(ksb + (sub * 64 + 32 + qn) * 128 + ((ch ^ (qn & 7)) * 16));
        s0 = __builtin_amdgcn_mfma_f32_32x32x16_bf16(kf0, qf[ks], s0, 0, 0, 0);
        s1 = __builtin_amdgcn_mfma_f32_32x32x16_bf16(kf1, qf[ks], s1, 0, 0, 0);
      }

      // V A-fragments hoisted: A[m=d][k=key], d = dm*32+qn, key = sub*64+16*ks2+8*h5+j
      bf16x8 vf[2][4];
#pragma unroll
      for (int dm = 0; dm < 2; dm++)
#pragma unroll
        for (int ks2 = 0; ks2 < 4; ks2++) {
          int d = dm * 32 + qn;
          int ch16 = 8 * sub + 2 * ks2 + h5;
          vf[dm][ks2] = *(const bf16x8*)(vsb + d * 256 + ((ch16 ^ (qn & 15)) * 16));
        }

      // softmax numerators: p = 2^s, lane-local (one q per lane), no shuffles
      float p0[16], p1[16];
      float sum = 0.f;
#pragma unroll
      for (int r = 0; r < 16; r++) {
        p0[r] = __builtin_amdgcn_exp2f(s0[r]);
        p1[r] = __builtin_amdgcn_exp2f(s1[r]);
        sum += p0[r] + p1[r];
      }
      lsum += sum;

      // P -> Ps[q][key]: C row = key_in_32 = (reg&3)+8*(reg>>2)+4*h5; chunk = 4*km+g
#pragma unroll
      for (int g = 0; g < 4; g++) {
        uint2 v0, v1;
        v0.x = pk2t(p0[4 * g], p0[4 * g + 1]);
        v0.y = pk2t(p0[4 * g + 2], p0[4 * g + 3]);
        v1.x = pk2t(p1[4 * g], p1[4 * g + 1]);
        v1.y = pk2t(p1[4 * g + 2], p1[4 * g + 3]);
        *(uint2*)(psw + qn * 128 + ((g ^ (qn & 7)) * 16) + h5 * 8) = v0;
        *(uint2*)(psw + qn * 128 + (((4 + g) ^ (qn & 7)) * 16) + h5 * 8) = v1;
      }

      // P B-fragments: B[k=key][n=q], key = 16*ks2 + 8*h5 + j
      bf16x8 pf[4];
#pragma unroll
      for (int ks2 = 0; ks2 < 4; ks2++)
        pf[ks2] = *(const bf16x8*)(psw + qn * 128 + (((2 * ks2 + h5) ^ (qn & 7)) * 16));

      // O^T[d][q] += V^T · P^T
#pragma unroll
      for (int ks2 = 0; ks2 < 4; ks2++) {
        o[0] = __builtin_amdgcn_mfma_f32_32x32x16_bf16(vf[0][ks2], pf[ks2], o[0], 0, 0, 0);
        o[1] = __builtin_amdgcn_mfma_f32_32x32x16_bf16(vf[1][ks2], pf[ks2], o[1], 0, 0, 0);
      }
    }
  }

  // finalize: single cross-lane reduction for l, then normalize + store.
  lsum += __shfl_xor(lsum, 32);
  float il = 1.0f / lsum;
  int row = b * SS + q0 + w * 32 + qn;
#pragma unroll
  for (int dm = 0; dm < 2; dm++)
#pragma unroll
    for (int g = 0; g < 4; g++) {
      int d = dm * 32 + 8 * g + 4 * h5;
      uint2 v;
      v.x = pk2(o[dm][4 * g] * il, o[dm][4 * g + 1] * il);
      v.y = pk2(o[dm][4 * g + 2] * il, o[dm][4 * g + 3] * il);
      *(uint2*)&attn[(size_t)row * DD + hcol + d] = v;
    }
}

extern "C" void kernel_launch(void* const* d_in, const int* in_sizes, int n_in,
                              void* d_out, int out_size, void* d_ws, size_t ws_size,
                              hipStream_t stream) {
  const float* x      = (const float*)d_in[0];
  const float* w_qkv  = (const float*)d_in[1];
  const float* b_qkv  = (const float*)d_in[2];
  const float* w_proj = (const float*)d_in[3];
  const float* b_proj = (const float*)d_in[4];
  float* out = (float*)d_out;

  u16* ws     = (u16*)d_ws;
  u16* x_bf   = ws;                                  // 4M u16
  u16* wqkvT  = x_bf   + (size_t)MROWS * KD;         // 3M
  u16* wprojT = wqkvT  + (size_t)NQKV * KD;          // 1M
  u16* qkv    = wprojT + (size_t)DD * KD;            // 12M (V region unused)
  u16* attn   = qkv    + (size_t)MROWS * NQKV;       // 4M
  u16* vt     = attn   + (size_t)MROWS * DD;         // 4M

  k_prep<<<3072, 256, 0, stream>>>(x, w_qkv, w_proj, x_bf, wqkvT, wprojT);
  k_gemm<2, 128><<<dim3(NQKV / 128, MROWS / 128), 256, 0, stream>>>(x_bf, wqkvT, b_qkv, qkv, vt, MROWS, NQKV, KD);
  k_attn<<<2 * HH * (SS / 128), 256, 0, stream>>>(qkv, vt, attn);
  k_gemm<0, 64><<<dim3(DD / 128, MROWS / 64), 256, 0, stream>>>(attn, wprojT, b_proj, out, nullptr, MROWS, DD, KD);
}